// Round 9
// baseline (386.570 us; speedup 1.0000x reference)
//
#include <hip/hip_runtime.h>
#include <hip/hip_bf16.h>
#include <cstdint>

#define NEG_SLOPE 0.2f

typedef __bf16 bf16x8 __attribute__((ext_vector_type(8)));
typedef float  f32x4  __attribute__((ext_vector_type(4)));

__device__ __forceinline__ unsigned short f2bf(float f) {
    unsigned int u = __float_as_uint(f);
    u += 0x7fffu + ((u >> 16) & 1u);          // round-to-nearest-even
    return (unsigned short)(u >> 16);
}
__device__ __forceinline__ float bf2f(unsigned short u) {
    return __uint_as_float((unsigned int)u << 16);
}
__device__ __forceinline__ void fma2(float2& a, float ex, unsigned int u) {
    a.x = fmaf(ex, __uint_as_float(u << 16),         a.x);
    a.y = fmaf(ex, __uint_as_float(u & 0xffff0000u), a.y);
}

// ---------------- prep: f2bf(W) + build_x (+ self-loop CSR seed) + gcnt ----------------
__global__ void prep_kernel(const float* __restrict__ W1, int n1,
                            const float* __restrict__ W2, int n2,
                            const float* __restrict__ W3, int n3,
                            unsigned short* __restrict__ w1b, unsigned short* __restrict__ w2b,
                            unsigned short* __restrict__ w3b,
                            const int* __restrict__ ids, const float* __restrict__ degs,
                            const float* __restrict__ emb, unsigned short* __restrict__ x,
                            int* __restrict__ cnt, int* __restrict__ bucket,
                            int* __restrict__ n_over,
                            const int* __restrict__ batch, int* __restrict__ gcnt,
                            int Nn, int G, int bW, int bX)
{
    int b = blockIdx.x;
    if (b < bW) {
        int i = b * 256 + threadIdx.x;
        if (i < n1) w1b[i] = f2bf(W1[i]);
        int j = i - n1;
        if (j >= 0 && j < n2) w2b[j] = f2bf(W2[j]);
        int k = j - n2;
        if (k >= 0 && k < n3) w3b[k] = f2bf(W3[k]);
    } else if (b < bX) {
        int node = (b - bW) * 4 + (threadIdx.x >> 6);
        int lane = threadIdx.x & 63;
        if (node < Nn) {
            int id = ids[node];
            float v;
            if (lane < 62) v = emb[(size_t)id * 62 + lane];
            else           v = degs[node * 2 + (lane - 62)];
            x[(size_t)node * 64 + lane] = f2bf(v);
            if (lane == 0) {                       // self-loop seed: slot 0
                cnt[node] = 1;
                bucket[(size_t)node * 64] = node;
            }
        }
    } else {
        int g = threadIdx.x;
        if (g < G) {
            int lo0 = 0, hi = Nn;
            while (lo0 < hi) { int mid = (lo0 + hi) >> 1; if (batch[mid] < g) lo0 = mid + 1; else hi = mid; }
            int lo1 = lo0; hi = Nn;
            while (lo1 < hi) { int mid = (lo1 + hi) >> 1; if (batch[mid] < g + 1) lo1 = mid + 1; else hi = mid; }
            gcnt[g] = lo1 - lo0;
        }
        if (threadIdx.x == 255) *n_over = 0;
    }
}

// ---------------- fused: bf16 MFMA GEMM (64x64/wave) + edge scatter ----------------
__global__ void gemm_scatter(const unsigned short* __restrict__ X, const unsigned short* __restrict__ Wb,
                             unsigned short* __restrict__ Hout,
                             const float* __restrict__ aSrc, const float* __restrict__ aDst,
                             float* __restrict__ a_s, float* __restrict__ a_d,
                             int Nn, int K, int F, int gemmB,
                             const int* __restrict__ esrc, const int* __restrict__ edst,
                             int* __restrict__ cnt, int* __restrict__ bucket,
                             int* __restrict__ ovd, int* __restrict__ ovs, int* __restrict__ n_over,
                             int E0)
{
    if (blockIdx.x >= gemmB) {
        int base = (blockIdx.x - gemmB) * 1024 + threadIdx.x;
        int sv[4], dv[4], pv[4];
        bool ok[4];
#pragma unroll
        for (int k = 0; k < 4; ++k) {
            int e = base + k * 256;
            ok[k] = (e < E0);
            if (ok[k]) { sv[k] = esrc[e]; dv[k] = edst[e]; }
        }
#pragma unroll
        for (int k = 0; k < 4; ++k)
            if (ok[k]) pv[k] = atomicAdd(&cnt[dv[k]], 1);
#pragma unroll
        for (int k = 0; k < 4; ++k) {
            if (ok[k]) {
                if (pv[k] < 64) bucket[(size_t)dv[k] * 64 + pv[k]] = sv[k];
                else {
                    int o = atomicAdd(n_over, 1);
                    ovd[o] = dv[k]; ovs[o] = sv[k];
                }
            }
        }
        return;
    }

    int wid  = (blockIdx.x * blockDim.x + threadIdx.x) >> 6;
    int lane = threadIdx.x & 63;
    int mtiles = (Nn + 63) >> 6;
    int ftiles = F >> 6;
    if (wid >= mtiles * ftiles) return;
    int ft = wid % ftiles;
    int mt = wid / ftiles;
    int m0 = mt << 6, f0 = ft << 6;
    int r = lane & 15, g = lane >> 4, g4 = g << 2;

    const unsigned short* xrow[4];
#pragma unroll
    for (int ja = 0; ja < 4; ++ja) {
        int row = m0 + ja * 16 + r;
        if (row >= Nn) row = Nn - 1;
        xrow[ja] = X + (size_t)row * K + g * 8;
    }
    const unsigned short* wrow = Wb + (size_t)(f0 + r) * K + g * 8;
    const size_t wstep = (size_t)16 * K;

    f32x4 acc[4][4];
#pragma unroll
    for (int a = 0; a < 4; ++a)
#pragma unroll
        for (int b = 0; b < 4; ++b) acc[a][b] = f32x4{0.f, 0.f, 0.f, 0.f};

    for (int k0 = 0; k0 < K; k0 += 32) {
        bf16x8 av[4], bv[4];
#pragma unroll
        for (int ja = 0; ja < 4; ++ja) av[ja] = *reinterpret_cast<const bf16x8*>(xrow[ja] + k0);
#pragma unroll
        for (int jb = 0; jb < 4; ++jb) bv[jb] = *reinterpret_cast<const bf16x8*>(wrow + jb * wstep + k0);
#pragma unroll
        for (int ja = 0; ja < 4; ++ja)
#pragma unroll
            for (int jb = 0; jb < 4; ++jb)
                acc[ja][jb] = __builtin_amdgcn_mfma_f32_16x16x32_bf16(av[ja], bv[jb], acc[ja][jb], 0, 0, 0);
    }

#pragma unroll
    for (int ja = 0; ja < 4; ++ja)
#pragma unroll
        for (int q = 0; q < 4; ++q) {
            int row = m0 + ja * 16 + g4 + q;
            if (row < Nn) {
#pragma unroll
                for (int jb = 0; jb < 4; ++jb)
                    Hout[(size_t)row * F + f0 + jb * 16 + r] = f2bf(acc[ja][jb][q]);
            }
        }

    float ps[4][4], pd[4][4];
#pragma unroll
    for (int ja = 0; ja < 4; ++ja)
#pragma unroll
        for (int q = 0; q < 4; ++q) { ps[ja][q] = 0.f; pd[ja][q] = 0.f; }
#pragma unroll
    for (int jb = 0; jb < 4; ++jb) {
        float ws_ = aSrc[f0 + jb * 16 + r];
        float wd_ = aDst[f0 + jb * 16 + r];
#pragma unroll
        for (int ja = 0; ja < 4; ++ja)
#pragma unroll
            for (int q = 0; q < 4; ++q) {
                ps[ja][q] += acc[ja][jb][q] * ws_;
                pd[ja][q] += acc[ja][jb][q] * wd_;
            }
    }
#pragma unroll
    for (int off = 1; off < 16; off <<= 1)
#pragma unroll
        for (int ja = 0; ja < 4; ++ja)
#pragma unroll
            for (int q = 0; q < 4; ++q) {
                ps[ja][q] += __shfl_xor(ps[ja][q], off, 64);
                pd[ja][q] += __shfl_xor(pd[ja][q], off, 64);
            }
    if (r == 0) {
        int Hh = F >> 6;
#pragma unroll
        for (int ja = 0; ja < 4; ++ja)
#pragma unroll
            for (int q = 0; q < 4; ++q) {
                int n = m0 + ja * 16 + g4 + q;
                if (n < Nn) {
                    a_s[(size_t)n * Hh + ft] = ps[ja][q];
                    a_d[(size_t)n * Hh + ft] = pd[ja][q];
                }
            }
    }
}

// ---------------- plain GEMM (layers 2,3) ----------------
__global__ void gemm_mfma(const unsigned short* __restrict__ X, const unsigned short* __restrict__ Wb,
                          unsigned short* __restrict__ Hout,
                          const float* __restrict__ aSrc, const float* __restrict__ aDst,
                          float* __restrict__ a_s, float* __restrict__ a_d,
                          int Nn, int K, int F)
{
    int wid  = (blockIdx.x * blockDim.x + threadIdx.x) >> 6;
    int lane = threadIdx.x & 63;
    int mtiles = (Nn + 63) >> 6;
    int ftiles = F >> 6;
    if (wid >= mtiles * ftiles) return;
    int ft = wid % ftiles;
    int mt = wid / ftiles;
    int m0 = mt << 6, f0 = ft << 6;
    int r = lane & 15, g = lane >> 4, g4 = g << 2;

    const unsigned short* xrow[4];
#pragma unroll
    for (int ja = 0; ja < 4; ++ja) {
        int row = m0 + ja * 16 + r;
        if (row >= Nn) row = Nn - 1;
        xrow[ja] = X + (size_t)row * K + g * 8;
    }
    const unsigned short* wrow = Wb + (size_t)(f0 + r) * K + g * 8;
    const size_t wstep = (size_t)16 * K;

    f32x4 acc[4][4];
#pragma unroll
    for (int a = 0; a < 4; ++a)
#pragma unroll
        for (int b = 0; b < 4; ++b) acc[a][b] = f32x4{0.f, 0.f, 0.f, 0.f};

    for (int k0 = 0; k0 < K; k0 += 32) {
        bf16x8 av[4], bv[4];
#pragma unroll
        for (int ja = 0; ja < 4; ++ja) av[ja] = *reinterpret_cast<const bf16x8*>(xrow[ja] + k0);
#pragma unroll
        for (int jb = 0; jb < 4; ++jb) bv[jb] = *reinterpret_cast<const bf16x8*>(wrow + jb * wstep + k0);
#pragma unroll
        for (int ja = 0; ja < 4; ++ja)
#pragma unroll
            for (int jb = 0; jb < 4; ++jb)
                acc[ja][jb] = __builtin_amdgcn_mfma_f32_16x16x32_bf16(av[ja], bv[jb], acc[ja][jb], 0, 0, 0);
    }

#pragma unroll
    for (int ja = 0; ja < 4; ++ja)
#pragma unroll
        for (int q = 0; q < 4; ++q) {
            int row = m0 + ja * 16 + g4 + q;
            if (row < Nn) {
#pragma unroll
                for (int jb = 0; jb < 4; ++jb)
                    Hout[(size_t)row * F + f0 + jb * 16 + r] = f2bf(acc[ja][jb][q]);
            }
        }

    float ps[4][4], pd[4][4];
#pragma unroll
    for (int ja = 0; ja < 4; ++ja)
#pragma unroll
        for (int q = 0; q < 4; ++q) { ps[ja][q] = 0.f; pd[ja][q] = 0.f; }
#pragma unroll
    for (int jb = 0; jb < 4; ++jb) {
        float ws_ = aSrc[f0 + jb * 16 + r];
        float wd_ = aDst[f0 + jb * 16 + r];
#pragma unroll
        for (int ja = 0; ja < 4; ++ja)
#pragma unroll
            for (int q = 0; q < 4; ++q) {
                ps[ja][q] += acc[ja][jb][q] * ws_;
                pd[ja][q] += acc[ja][jb][q] * wd_;
            }
    }
#pragma unroll
    for (int off = 1; off < 16; off <<= 1)
#pragma unroll
        for (int ja = 0; ja < 4; ++ja)
#pragma unroll
            for (int q = 0; q < 4; ++q) {
                ps[ja][q] += __shfl_xor(ps[ja][q], off, 64);
                pd[ja][q] += __shfl_xor(pd[ja][q], off, 64);
            }
    if (r == 0) {
        int Hh = F >> 6;
#pragma unroll
        for (int ja = 0; ja < 4; ++ja)
#pragma unroll
            for (int q = 0; q < 4; ++q) {
                int n = m0 + ja * 16 + g4 + q;
                if (n < Nn) {
                    a_s[(size_t)n * Hh + ft] = ps[ja][q];
                    a_d[(size_t)n * Hh + ft] = pd[ja][q];
                }
            }
    }
}

// ---------------- H=4 aggregation, head-split: 1 wave = 1 node x 1 head ----------------
// blockIdx%8 -> XCD (round-robin heuristic); head = xcd/2 so each head's gather
// stays on one XCD pair, cutting per-XCD compulsory H traffic 4x. Correct under
// any block->XCD mapping (pure index remap).
__global__ void aggregate4_hs(const unsigned short* __restrict__ Hb,
                              const float* __restrict__ a_s, const float* __restrict__ a_d,
                              const int* __restrict__ cnt, const int* __restrict__ bucket,
                              const int* __restrict__ ovd, const int* __restrict__ ovs,
                              const int* __restrict__ n_over,
                              const float* __restrict__ bias,
                              unsigned short* __restrict__ out, int Nn)
{
    __shared__ uint2 s_pk[4][64];
    int b = blockIdx.x;
    int xcd = b & 7, slot = b >> 3;
    int head = xcd >> 1;
    int nb = slot * 2 + (xcd & 1);
    int w = threadIdx.x >> 6;
    int node = nb * 4 + w;
    int lane = threadIdx.x & 63;
    if (node >= Nn) return;
    int deg = cnt[node];
    float adh = a_d[(size_t)node * 4 + head];

    if (deg <= 64) {
        bool act = lane < deg;
        int sn = act ? bucket[(size_t)node * 64 + lane] : 0;
        float t = a_s[(size_t)sn * 4 + head] + adh;
        t = (t > 0.f) ? t : NEG_SLOPE * t;
        float v = act ? t : -1e30f;
        float m = v;
#pragma unroll
        for (int off = 32; off >= 1; off >>= 1)
            m = fmaxf(m, __shfl_xor(m, off, 64));
        float e = act ? __expf(v - m) : 0.f;
        float s = e;
#pragma unroll
        for (int off = 32; off >= 1; off >>= 1)
            s += __shfl_xor(s, off, 64);

        s_pk[w][lane] = make_uint2((unsigned int)sn, __float_as_uint(e));
        asm volatile("s_waitcnt lgkmcnt(0)" ::: "memory");

        // pass C: 8 edges/iter, 16 lanes per edge, 4 ch/lane (uint2 = 8 B slice)
        int laneq = lane & 15, qtr = lane >> 4;
        float2 acc2[2];
        acc2[0] = make_float2(0.f, 0.f);
        acc2[1] = make_float2(0.f, 0.f);
        int j = 0;
        for (; j + 8 <= deg; j += 8) {
            uint2 pkA = s_pk[w][j + qtr];
            uint2 pkB = s_pk[w][j + 4 + qtr];
            const uint2 a = *reinterpret_cast<const uint2*>(Hb + (size_t)pkA.x * 256 + head * 64 + laneq * 4);
            const uint2 bb = *reinterpret_cast<const uint2*>(Hb + (size_t)pkB.x * 256 + head * 64 + laneq * 4);
            float exA = __uint_as_float(pkA.y);
            float exB = __uint_as_float(pkB.y);
            fma2(acc2[0], exA, a.x);  fma2(acc2[1], exA, a.y);
            fma2(acc2[0], exB, bb.x); fma2(acc2[1], exB, bb.y);
        }
        for (; j < deg; j += 4) {
            uint2 pk = s_pk[w][j + qtr];
            float ex = __uint_as_float(pk.y);
            const uint2 u = *reinterpret_cast<const uint2*>(Hb + (size_t)pk.x * 256 + head * 64 + laneq * 4);
            fma2(acc2[0], ex, u.x); fma2(acc2[1], ex, u.y);
        }
#pragma unroll
        for (int k = 0; k < 2; ++k) {
            acc2[k].x += __shfl_xor(acc2[k].x, 32, 64);
            acc2[k].y += __shfl_xor(acc2[k].y, 32, 64);
            acc2[k].x += __shfl_xor(acc2[k].x, 16, 64);
            acc2[k].y += __shfl_xor(acc2[k].y, 16, 64);
        }
        if (lane < 16) {
            float inv = 1.f / (s + 1e-16f);
            int fb = head * 64 + lane * 4;
            float t0 = acc2[0].x * inv + bias[fb + 0];
            float t1 = acc2[0].y * inv + bias[fb + 1];
            float t2 = acc2[1].x * inv + bias[fb + 2];
            float t3 = acc2[1].y * inv + bias[fb + 3];
            unsigned int p0 = (unsigned int)f2bf(t0 > 0.f ? t0 : 0.f) |
                              ((unsigned int)f2bf(t1 > 0.f ? t1 : 0.f) << 16);
            unsigned int p1 = (unsigned int)f2bf(t2 > 0.f ? t2 : 0.f) |
                              ((unsigned int)f2bf(t3 > 0.f ? t3 : 0.f) << 16);
            *reinterpret_cast<uint2*>(out + (size_t)node * 256 + fb) = make_uint2(p0, p1);
        }
        return;
    }

    // -------- slow path (deg > 64): exact; 1 ch per lane --------
    int nov = *n_over;
    float m = -1e30f, s = 0.f;
    {
        int sn = bucket[(size_t)node * 64 + lane];
        float t = a_s[(size_t)sn * 4 + head] + adh;
        t = (t > 0.f) ? t : NEG_SLOPE * t;
        m = t;
    }
    for (int i = lane; i < nov; i += 64) {
        if (ovd[i] != node) continue;
        float t = a_s[(size_t)ovs[i] * 4 + head] + adh;
        t = (t > 0.f) ? t : NEG_SLOPE * t;
        m = fmaxf(m, t);
    }
#pragma unroll
    for (int off = 32; off >= 1; off >>= 1) m = fmaxf(m, __shfl_xor(m, off, 64));
    {
        int sn = bucket[(size_t)node * 64 + lane];
        float t = a_s[(size_t)sn * 4 + head] + adh;
        t = (t > 0.f) ? t : NEG_SLOPE * t;
        s += __expf(t - m);
    }
    for (int i = lane; i < nov; i += 64) {
        if (ovd[i] != node) continue;
        float t = a_s[(size_t)ovs[i] * 4 + head] + adh;
        t = (t > 0.f) ? t : NEG_SLOPE * t;
        s += __expf(t - m);
    }
#pragma unroll
    for (int off = 32; off >= 1; off >>= 1) s += __shfl_xor(s, off, 64);
    float inv = 1.f / (s + 1e-16f);

    float acc = 0.f;                        // ch = lane
    for (int j = 0; j < 64; ++j) {
        int sn = bucket[(size_t)node * 64 + j];
        float t = a_s[(size_t)sn * 4 + head] + adh;
        t = (t > 0.f) ? t : NEG_SLOPE * t;
        float ex = __expf(t - m);
        acc += ex * bf2f(Hb[(size_t)sn * 256 + head * 64 + lane]);
    }
    for (int i = 0; i < nov; ++i) {
        if (ovd[i] != node) continue;
        int sn = ovs[i];
        float t = a_s[(size_t)sn * 4 + head] + adh;
        t = (t > 0.f) ? t : NEG_SLOPE * t;
        float ex = __expf(t - m);
        acc += ex * bf2f(Hb[(size_t)sn * 256 + head * 64 + lane]);
    }
    float t = acc * inv + bias[head * 64 + lane];
    out[(size_t)node * 256 + head * 64 + lane] = f2bf(t > 0.f ? t : 0.f);
}

// ---------------- H=1 softmax + aggregation (bucket CSR) ----------------
template<int H>
__global__ void aggregate_kernel(const unsigned short* __restrict__ Hb,
                                 const float* __restrict__ a_s, const float* __restrict__ a_d,
                                 const int* __restrict__ cnt, const int* __restrict__ bucket,
                                 const int* __restrict__ ovd, const int* __restrict__ ovs,
                                 const int* __restrict__ n_over,
                                 const float* __restrict__ bias,
                                 unsigned short* __restrict__ out, int Nn)
{
    constexpr int F = H * 64;
    constexpr int VEC = F / 64;
    __shared__ uint2 s_pk[4][64][H];
    int w = threadIdx.x >> 6;
    int node = blockIdx.x * 4 + w;
    int lane = threadIdx.x & 63;
    if (node >= Nn) return;
    int deg = cnt[node];

    float adn[H];
#pragma unroll
    for (int h = 0; h < H; ++h) adn[h] = a_d[(size_t)node * H + h];

    if (deg <= 64) {
        bool act = lane < deg;
        int sn = act ? bucket[(size_t)node * 64 + lane] : 0;
        float v[H];
        {
            float t = a_s[sn] + adn[0];
            t = (t > 0.f) ? t : NEG_SLOPE * t;
            v[0] = act ? t : -1e30f;
        }
        float m[H], e[H], s[H];
#pragma unroll
        for (int h = 0; h < H; ++h) {
            m[h] = v[h];
#pragma unroll
            for (int off = 32; off >= 1; off >>= 1)
                m[h] = fmaxf(m[h], __shfl_xor(m[h], off, 64));
        }
#pragma unroll
        for (int h = 0; h < H; ++h) {
            e[h] = act ? __expf(v[h] - m[h]) : 0.f;
            s[h] = e[h];
#pragma unroll
            for (int off = 32; off >= 1; off >>= 1)
                s[h] += __shfl_xor(s[h], off, 64);
        }

#pragma unroll
        for (int h = 0; h < H; ++h)
            s_pk[w][lane][h] = make_uint2((unsigned int)sn, __float_as_uint(e[h]));
        asm volatile("s_waitcnt lgkmcnt(0)" ::: "memory");

        // 16 edges / iter (2 batches of 8): 8 lanes per edge, 8 ch/lane
        int laneo = lane & 7, oct = lane >> 3;
        float2 acc2[4];
#pragma unroll
        for (int k = 0; k < 4; ++k) acc2[k] = make_float2(0.f, 0.f);
        int j = 0;
        for (; j + 16 <= deg; j += 16) {
            uint2 pkA = s_pk[w][j + oct][0];
            uint2 pkB = s_pk[w][j + 8 + oct][0];
            const uint4 a = *reinterpret_cast<const uint4*>(Hb + (size_t)pkA.x * 64 + laneo * 8);
            const uint4 b = *reinterpret_cast<const uint4*>(Hb + (size_t)pkB.x * 64 + laneo * 8);
            float exA = __uint_as_float(pkA.y);
            float exB = __uint_as_float(pkB.y);
            fma2(acc2[0], exA, a.x); fma2(acc2[1], exA, a.y);
            fma2(acc2[2], exA, a.z); fma2(acc2[3], exA, a.w);
            fma2(acc2[0], exB, b.x); fma2(acc2[1], exB, b.y);
            fma2(acc2[2], exB, b.z); fma2(acc2[3], exB, b.w);
        }
        for (; j < deg; j += 8) {
            uint2 pk = s_pk[w][j + oct][0];
            float ex = __uint_as_float(pk.y);
            const uint4 u = *reinterpret_cast<const uint4*>(Hb + (size_t)pk.x * 64 + laneo * 8);
            fma2(acc2[0], ex, u.x); fma2(acc2[1], ex, u.y);
            fma2(acc2[2], ex, u.z); fma2(acc2[3], ex, u.w);
        }
#pragma unroll
        for (int k = 0; k < 4; ++k) {
            acc2[k].x += __shfl_xor(acc2[k].x, 32, 64);
            acc2[k].y += __shfl_xor(acc2[k].y, 32, 64);
            acc2[k].x += __shfl_xor(acc2[k].x, 16, 64);
            acc2[k].y += __shfl_xor(acc2[k].y, 16, 64);
            acc2[k].x += __shfl_xor(acc2[k].x, 8, 64);
            acc2[k].y += __shfl_xor(acc2[k].y, 8, 64);
        }
        if (lane < 8) {
            float inv = 1.f / (s[0] + 1e-16f);
            unsigned int pk4[4];
#pragma unroll
            for (int k = 0; k < 4; ++k) {
                float t0 = acc2[k].x * inv + bias[lane * 8 + 2 * k];
                float t1 = acc2[k].y * inv + bias[lane * 8 + 2 * k + 1];
                unsigned int lo = f2bf(t0 > 0.f ? t0 : 0.f);
                unsigned int hi = f2bf(t1 > 0.f ? t1 : 0.f);
                pk4[k] = lo | (hi << 16);
            }
            *reinterpret_cast<uint4*>(out + (size_t)node * 64 + lane * 8) =
                make_uint4(pk4[0], pk4[1], pk4[2], pk4[3]);
        }
        return;
    }

    // -------- slow path (deg > 64) --------
    int nov = *n_over;
    int head = 0;
    float m[H], s[H];
#pragma unroll
    for (int h = 0; h < H; ++h) { m[h] = -1e30f; s[h] = 0.f; }
    {
        int sn = bucket[(size_t)node * 64 + lane];
        float t = a_s[(size_t)sn * H] + adn[0];
        t = (t > 0.f) ? t : NEG_SLOPE * t;
        m[0] = fmaxf(m[0], t);
    }
    for (int i = lane; i < nov; i += 64) {
        if (ovd[i] != node) continue;
        float t = a_s[(size_t)ovs[i] * H] + adn[0];
        t = (t > 0.f) ? t : NEG_SLOPE * t;
        m[0] = fmaxf(m[0], t);
    }
#pragma unroll
    for (int off = 32; off >= 1; off >>= 1) m[0] = fmaxf(m[0], __shfl_xor(m[0], off, 64));
    {
        int sn = bucket[(size_t)node * 64 + lane];
        float t = a_s[(size_t)sn * H] + adn[0];
        t = (t > 0.f) ? t : NEG_SLOPE * t;
        s[0] += __expf(t - m[0]);
    }
    for (int i = lane; i < nov; i += 64) {
        if (ovd[i] != node) continue;
        float t = a_s[(size_t)ovs[i] * H] + adn[0];
        t = (t > 0.f) ? t : NEG_SLOPE * t;
        s[0] += __expf(t - m[0]);
    }
#pragma unroll
    for (int off = 32; off >= 1; off >>= 1) s[0] += __shfl_xor(s[0], off, 64);

    float mh = m[0], sh = s[0], adh = adn[0];
    float inv = 1.f / (sh + 1e-16f);
    float acc[VEC];
#pragma unroll
    for (int k = 0; k < VEC; ++k) acc[k] = 0.f;
    for (int j = 0; j < 64; ++j) {
        int sn = bucket[(size_t)node * 64 + j];
        float t = a_s[(size_t)sn * H + head] + adh;
        t = (t > 0.f) ? t : NEG_SLOPE * t;
        float ex = __expf(t - mh);
        const unsigned short* hp = Hb + (size_t)sn * F + lane * VEC;
#pragma unroll
        for (int k = 0; k < VEC; ++k) acc[k] += ex * bf2f(hp[k]);
    }
    for (int i = 0; i < nov; ++i) {
        if (ovd[i] != node) continue;
        int sn = ovs[i];
        float t = a_s[(size_t)sn * H + head] + adh;
        t = (t > 0.f) ? t : NEG_SLOPE * t;
        float ex = __expf(t - mh);
        const unsigned short* hp = Hb + (size_t)sn * F + lane * VEC;
#pragma unroll
        for (int k = 0; k < VEC; ++k) acc[k] += ex * bf2f(hp[k]);
    }
#pragma unroll
    for (int k = 0; k < VEC; ++k) {
        int f = lane * VEC + k;
        float t = acc[k] * inv + bias[f];
        out[(size_t)node * F + f] = f2bf(t > 0.f ? t : 0.f);
    }
}

// ---------------- global mean pool (sums, bf16 input) ----------------
__global__ void pool_kernel(const unsigned short* __restrict__ x, const int* __restrict__ batch,
                            float* __restrict__ gsums, int Nn)
{
    int lane = threadIdx.x;        // blockDim = 64
    int n0 = blockIdx.x * 64;
    if (n0 >= Nn) return;
    int nend = min(n0 + 64, Nn);
    float acc = 0.f;
    int gcur = batch[n0];
    for (int n = n0; n < nend; ++n) {
        int g = batch[n];
        if (g != gcur) {
            atomicAdd(&gsums[gcur * 64 + lane], acc);
            acc = 0.f;
            gcur = g;
        }
        acc += bf2f(x[(size_t)n * 64 + lane]);
    }
    atomicAdd(&gsums[gcur * 64 + lane], acc);
}

// ---------------- final linear ----------------
__global__ void final_kernel(const float* __restrict__ gsums, const int* __restrict__ gcnt,
                             const float* __restrict__ linW, const float* __restrict__ linb,
                             float* __restrict__ out, int G)
{
    int t = threadIdx.x;
    if (t >= G * 10) return;
    int g = t / 10, j = t % 10;
    float cnt = (float)max(gcnt[g], 1);
    float acc = 0.f;
#pragma unroll
    for (int c = 0; c < 64; ++c) acc += gsums[g * 64 + c] * linW[j * 64 + c];
    out[g * 10 + j] = acc / cnt + linb[j];
}

extern "C" void kernel_launch(void* const* d_in, const int* in_sizes, int n_in,
                              void* d_out, int out_size, void* d_ws, size_t ws_size,
                              hipStream_t stream)
{
    const int*   x_ids    = (const int*)d_in[0];
    const float* degrees  = (const float*)d_in[1];
    const int*   edge_src = (const int*)d_in[2];
    const int*   edge_dst = (const int*)d_in[3];
    const int*   batch    = (const int*)d_in[4];
    const float* emb      = (const float*)d_in[5];
    const float* W1  = (const float*)d_in[6];
    const float* as1 = (const float*)d_in[7];
    const float* ad1 = (const float*)d_in[8];
    const float* b1  = (const float*)d_in[9];
    const float* W2  = (const float*)d_in[10];
    const float* as2 = (const float*)d_in[11];
    const float* ad2 = (const float*)d_in[12];
    const float* b2  = (const float*)d_in[13];
    const float* W3  = (const float*)d_in[14];
    const float* as3 = (const float*)d_in[15];
    const float* ad3 = (const float*)d_in[16];
    const float* b3  = (const float*)d_in[17];
    const float* linW = (const float*)d_in[18];
    const float* linb = (const float*)d_in[19];

    const int N  = in_sizes[0];
    const int E0 = in_sizes[2];
    const int E2 = E0 + N;
    const int G  = out_size / 10;
    const int nW1 = in_sizes[6], nW2 = in_sizes[10], nW3 = in_sizes[14];

    char* p = (char*)d_ws;
    size_t off = 0;
    auto take = [&](size_t bytes) {
        void* q = p + off;
        off = (off + bytes + 255) & ~(size_t)255;
        return q;
    };
    unsigned short* xA  = (unsigned short*)take((size_t)N * 256 * 2);
    unsigned short* xB  = (unsigned short*)take((size_t)N * 256 * 2);
    float* a_s     = (float*)take((size_t)N * 4 * 4);
    float* a_d     = (float*)take((size_t)N * 4 * 4);
    int*   cnt     = (int*)take((size_t)(N + 64) * 4);   // cnt[N] followed by n_over
    int*   n_over  = cnt + N;
    int*   bucket  = (int*)take((size_t)N * 64 * 4);
    int*   ovd     = (int*)take((size_t)E2 * 4);
    int*   ovs     = (int*)take((size_t)E2 * 4);
    float* gsums   = (float*)take((size_t)G * 64 * 4);
    int*   gcnt    = (int*)take((size_t)G * 4);
    unsigned short* w1b = (unsigned short*)take((size_t)nW1 * 2);
    unsigned short* w2b = (unsigned short*)take((size_t)nW2 * 2);
    unsigned short* w3b = (unsigned short*)take((size_t)nW3 * 2);

    hipMemsetAsync(gsums, 0, (size_t)G * 64 * 4, stream);

    const int nodeBlocks4 = (N + 3) / 4;

    // prep block partition
    const int nWtot = nW1 + nW2 + nW3;
    const int bW = (nWtot + 255) / 256;
    const int bX = bW + nodeBlocks4;
    prep_kernel<<<bX + 1, 256, 0, stream>>>(W1, nW1, W2, nW2, W3, nW3, w1b, w2b, w3b,
                                            x_ids, degrees, emb, xA,
                                            cnt, bucket, n_over, batch, gcnt,
                                            N, G, bW, bX);

    const int mtiles = (N + 63) / 64;
    auto gemmBlocks = [&](int ftiles) { return (mtiles * ftiles + 3) / 4; };

    // head-split aggregate grid: 8 * ceil(nodeBlocks4 / 2)
    const int hsBlocks = 8 * ((nodeBlocks4 + 1) / 2);

    // ---- layer 1 (fused with edge scatter): 64 -> 4x64 concat ----
    const int gemmB1   = gemmBlocks(4);
    const int scatterB = (E0 + 1023) / 1024;
    gemm_scatter<<<gemmB1 + scatterB, 256, 0, stream>>>(xA, w1b, xB, as1, ad1, a_s, a_d,
                                                        N, 64, 256, gemmB1,
                                                        edge_src, edge_dst, cnt, bucket,
                                                        ovd, ovs, n_over, E0);
    aggregate4_hs<<<hsBlocks, 256, 0, stream>>>(xB, a_s, a_d, cnt, bucket, ovd, ovs, n_over, b1, xA, N);
    // ---- layer 2: 256 -> 4x64 concat ----
    gemm_mfma<<<gemmBlocks(4), 256, 0, stream>>>(xA, w2b, xB, as2, ad2, a_s, a_d, N, 256, 256);
    aggregate4_hs<<<hsBlocks, 256, 0, stream>>>(xB, a_s, a_d, cnt, bucket, ovd, ovs, n_over, b2, xA, N);
    // ---- layer 3: 256 -> 1x64 (mean == identity) ----
    gemm_mfma<<<gemmBlocks(1), 256, 0, stream>>>(xA, w3b, xB, as3, ad3, a_s, a_d, N, 256, 64);
    aggregate_kernel<1><<<nodeBlocks4, 256, 0, stream>>>(xB, a_s, a_d, cnt, bucket, ovd, ovs, n_over, b3, xA, N);

    pool_kernel<<<(N + 63) / 64, 64, 0, stream>>>(xA, batch, gsums, N);
    final_kernel<<<1, ((G * 10 + 63) / 64) * 64, 0, stream>>>(gsums, gcnt, linW, linb, (float*)d_out, G);
}

// Round 10
// 328.432 us; speedup vs baseline: 1.1770x; 1.1770x over previous
//
#include <hip/hip_runtime.h>
#include <hip/hip_bf16.h>
#include <cstdint>

#define NEG_SLOPE 0.2f

typedef __bf16 bf16x8 __attribute__((ext_vector_type(8)));
typedef float  f32x4  __attribute__((ext_vector_type(4)));

__device__ __forceinline__ unsigned short f2bf(float f) {
    unsigned int u = __float_as_uint(f);
    u += 0x7fffu + ((u >> 16) & 1u);          // round-to-nearest-even
    return (unsigned short)(u >> 16);
}
__device__ __forceinline__ float bf2f(unsigned short u) {
    return __uint_as_float((unsigned int)u << 16);
}
__device__ __forceinline__ void fma2(float2& a, float ex, unsigned int u) {
    a.x = fmaf(ex, __uint_as_float(u << 16),         a.x);
    a.y = fmaf(ex, __uint_as_float(u & 0xffff0000u), a.y);
}

// ---------------- prep: f2bf(W) + build_x (+ self-loop CSR seed) + gcnt ----------------
__global__ void prep_kernel(const float* __restrict__ W1, int n1,
                            const float* __restrict__ W2, int n2,
                            const float* __restrict__ W3, int n3,
                            unsigned short* __restrict__ w1b, unsigned short* __restrict__ w2b,
                            unsigned short* __restrict__ w3b,
                            const int* __restrict__ ids, const float* __restrict__ degs,
                            const float* __restrict__ emb, unsigned short* __restrict__ x,
                            int* __restrict__ cnt, int* __restrict__ bucket,
                            int* __restrict__ n_over,
                            const int* __restrict__ batch, int* __restrict__ gcnt,
                            int Nn, int G, int bW, int bX)
{
    int b = blockIdx.x;
    if (b < bW) {
        int i = b * 256 + threadIdx.x;
        if (i < n1) w1b[i] = f2bf(W1[i]);
        int j = i - n1;
        if (j >= 0 && j < n2) w2b[j] = f2bf(W2[j]);
        int k = j - n2;
        if (k >= 0 && k < n3) w3b[k] = f2bf(W3[k]);
    } else if (b < bX) {
        int node = (b - bW) * 4 + (threadIdx.x >> 6);
        int lane = threadIdx.x & 63;
        if (node < Nn) {
            int id = ids[node];
            float v;
            if (lane < 62) v = emb[(size_t)id * 62 + lane];
            else           v = degs[node * 2 + (lane - 62)];
            x[(size_t)node * 64 + lane] = f2bf(v);
            if (lane == 0) {                       // self-loop seed: slot 0
                cnt[node] = 1;
                bucket[(size_t)node * 64] = node;
            }
        }
    } else {
        int g = threadIdx.x;
        if (g < G) {
            int lo0 = 0, hi = Nn;
            while (lo0 < hi) { int mid = (lo0 + hi) >> 1; if (batch[mid] < g) lo0 = mid + 1; else hi = mid; }
            int lo1 = lo0; hi = Nn;
            while (lo1 < hi) { int mid = (lo1 + hi) >> 1; if (batch[mid] < g + 1) lo1 = mid + 1; else hi = mid; }
            gcnt[g] = lo1 - lo0;
        }
        if (threadIdx.x == 255) *n_over = 0;
    }
}

// ---------------- fused: bf16 MFMA GEMM (64x64/wave) + edge scatter (8-edge ILP) ----------------
__global__ void gemm_scatter(const unsigned short* __restrict__ X, const unsigned short* __restrict__ Wb,
                             unsigned short* __restrict__ Hout,
                             const float* __restrict__ aSrc, const float* __restrict__ aDst,
                             float* __restrict__ a_s, float* __restrict__ a_d,
                             int Nn, int K, int F, int gemmB,
                             const int* __restrict__ esrc, const int* __restrict__ edst,
                             int* __restrict__ cnt, int* __restrict__ bucket,
                             int* __restrict__ ovd, int* __restrict__ ovs, int* __restrict__ n_over,
                             int E0)
{
    if (blockIdx.x >= gemmB) {
        int base = (blockIdx.x - gemmB) * 2048 + threadIdx.x;
        int sv[8], dv[8], pv[8];
        bool ok[8];
#pragma unroll
        for (int k = 0; k < 8; ++k) {
            int e = base + k * 256;
            ok[k] = (e < E0);
            if (ok[k]) { sv[k] = esrc[e]; dv[k] = edst[e]; }
        }
#pragma unroll
        for (int k = 0; k < 8; ++k)
            if (ok[k]) pv[k] = atomicAdd(&cnt[dv[k]], 1);
#pragma unroll
        for (int k = 0; k < 8; ++k) {
            if (ok[k]) {
                if (pv[k] < 64) bucket[(size_t)dv[k] * 64 + pv[k]] = sv[k];
                else {
                    int o = atomicAdd(n_over, 1);
                    ovd[o] = dv[k]; ovs[o] = sv[k];
                }
            }
        }
        return;
    }

    int wid  = (blockIdx.x * blockDim.x + threadIdx.x) >> 6;
    int lane = threadIdx.x & 63;
    int mtiles = (Nn + 63) >> 6;
    int ftiles = F >> 6;
    if (wid >= mtiles * ftiles) return;
    int ft = wid % ftiles;              // block-local f-tiles: X-tile reuse within block
    int mt = wid / ftiles;
    int m0 = mt << 6, f0 = ft << 6;
    int r = lane & 15, g = lane >> 4, g4 = g << 2;

    const unsigned short* xrow[4];
#pragma unroll
    for (int ja = 0; ja < 4; ++ja) {
        int row = m0 + ja * 16 + r;
        if (row >= Nn) row = Nn - 1;
        xrow[ja] = X + (size_t)row * K + g * 8;
    }
    const unsigned short* wrow = Wb + (size_t)(f0 + r) * K + g * 8;
    const size_t wstep = (size_t)16 * K;

    f32x4 acc[4][4];
#pragma unroll
    for (int a = 0; a < 4; ++a)
#pragma unroll
        for (int b = 0; b < 4; ++b) acc[a][b] = f32x4{0.f, 0.f, 0.f, 0.f};

    for (int k0 = 0; k0 < K; k0 += 32) {
        bf16x8 av[4], bv[4];
#pragma unroll
        for (int ja = 0; ja < 4; ++ja) av[ja] = *reinterpret_cast<const bf16x8*>(xrow[ja] + k0);
#pragma unroll
        for (int jb = 0; jb < 4; ++jb) bv[jb] = *reinterpret_cast<const bf16x8*>(wrow + jb * wstep + k0);
#pragma unroll
        for (int ja = 0; ja < 4; ++ja)
#pragma unroll
            for (int jb = 0; jb < 4; ++jb)
                acc[ja][jb] = __builtin_amdgcn_mfma_f32_16x16x32_bf16(av[ja], bv[jb], acc[ja][jb], 0, 0, 0);
    }

#pragma unroll
    for (int ja = 0; ja < 4; ++ja)
#pragma unroll
        for (int q = 0; q < 4; ++q) {
            int row = m0 + ja * 16 + g4 + q;
            if (row < Nn) {
#pragma unroll
                for (int jb = 0; jb < 4; ++jb)
                    Hout[(size_t)row * F + f0 + jb * 16 + r] = f2bf(acc[ja][jb][q]);
            }
        }

    float ps[4][4], pd[4][4];
#pragma unroll
    for (int ja = 0; ja < 4; ++ja)
#pragma unroll
        for (int q = 0; q < 4; ++q) { ps[ja][q] = 0.f; pd[ja][q] = 0.f; }
#pragma unroll
    for (int jb = 0; jb < 4; ++jb) {
        float ws_ = aSrc[f0 + jb * 16 + r];
        float wd_ = aDst[f0 + jb * 16 + r];
#pragma unroll
        for (int ja = 0; ja < 4; ++ja)
#pragma unroll
            for (int q = 0; q < 4; ++q) {
                ps[ja][q] += acc[ja][jb][q] * ws_;
                pd[ja][q] += acc[ja][jb][q] * wd_;
            }
    }
#pragma unroll
    for (int off = 1; off < 16; off <<= 1)
#pragma unroll
        for (int ja = 0; ja < 4; ++ja)
#pragma unroll
            for (int q = 0; q < 4; ++q) {
                ps[ja][q] += __shfl_xor(ps[ja][q], off, 64);
                pd[ja][q] += __shfl_xor(pd[ja][q], off, 64);
            }
    if (r == 0) {
        int Hh = F >> 6;
#pragma unroll
        for (int ja = 0; ja < 4; ++ja)
#pragma unroll
            for (int q = 0; q < 4; ++q) {
                int n = m0 + ja * 16 + g4 + q;
                if (n < Nn) {
                    a_s[(size_t)n * Hh + ft] = ps[ja][q];
                    a_d[(size_t)n * Hh + ft] = pd[ja][q];
                }
            }
    }
}

// ---------------- plain GEMM (layers 2,3) ----------------
__global__ void gemm_mfma(const unsigned short* __restrict__ X, const unsigned short* __restrict__ Wb,
                          unsigned short* __restrict__ Hout,
                          const float* __restrict__ aSrc, const float* __restrict__ aDst,
                          float* __restrict__ a_s, float* __restrict__ a_d,
                          int Nn, int K, int F)
{
    int wid  = (blockIdx.x * blockDim.x + threadIdx.x) >> 6;
    int lane = threadIdx.x & 63;
    int mtiles = (Nn + 63) >> 6;
    int ftiles = F >> 6;
    if (wid >= mtiles * ftiles) return;
    int ft = wid % ftiles;
    int mt = wid / ftiles;
    int m0 = mt << 6, f0 = ft << 6;
    int r = lane & 15, g = lane >> 4, g4 = g << 2;

    const unsigned short* xrow[4];
#pragma unroll
    for (int ja = 0; ja < 4; ++ja) {
        int row = m0 + ja * 16 + r;
        if (row >= Nn) row = Nn - 1;
        xrow[ja] = X + (size_t)row * K + g * 8;
    }
    const unsigned short* wrow = Wb + (size_t)(f0 + r) * K + g * 8;
    const size_t wstep = (size_t)16 * K;

    f32x4 acc[4][4];
#pragma unroll
    for (int a = 0; a < 4; ++a)
#pragma unroll
        for (int b = 0; b < 4; ++b) acc[a][b] = f32x4{0.f, 0.f, 0.f, 0.f};

    for (int k0 = 0; k0 < K; k0 += 32) {
        bf16x8 av[4], bv[4];
#pragma unroll
        for (int ja = 0; ja < 4; ++ja) av[ja] = *reinterpret_cast<const bf16x8*>(xrow[ja] + k0);
#pragma unroll
        for (int jb = 0; jb < 4; ++jb) bv[jb] = *reinterpret_cast<const bf16x8*>(wrow + jb * wstep + k0);
#pragma unroll
        for (int ja = 0; ja < 4; ++ja)
#pragma unroll
            for (int jb = 0; jb < 4; ++jb)
                acc[ja][jb] = __builtin_amdgcn_mfma_f32_16x16x32_bf16(av[ja], bv[jb], acc[ja][jb], 0, 0, 0);
    }

#pragma unroll
    for (int ja = 0; ja < 4; ++ja)
#pragma unroll
        for (int q = 0; q < 4; ++q) {
            int row = m0 + ja * 16 + g4 + q;
            if (row < Nn) {
#pragma unroll
                for (int jb = 0; jb < 4; ++jb)
                    Hout[(size_t)row * F + f0 + jb * 16 + r] = f2bf(acc[ja][jb][q]);
            }
        }

    float ps[4][4], pd[4][4];
#pragma unroll
    for (int ja = 0; ja < 4; ++ja)
#pragma unroll
        for (int q = 0; q < 4; ++q) { ps[ja][q] = 0.f; pd[ja][q] = 0.f; }
#pragma unroll
    for (int jb = 0; jb < 4; ++jb) {
        float ws_ = aSrc[f0 + jb * 16 + r];
        float wd_ = aDst[f0 + jb * 16 + r];
#pragma unroll
        for (int ja = 0; ja < 4; ++ja)
#pragma unroll
            for (int q = 0; q < 4; ++q) {
                ps[ja][q] += acc[ja][jb][q] * ws_;
                pd[ja][q] += acc[ja][jb][q] * wd_;
            }
    }
#pragma unroll
    for (int off = 1; off < 16; off <<= 1)
#pragma unroll
        for (int ja = 0; ja < 4; ++ja)
#pragma unroll
            for (int q = 0; q < 4; ++q) {
                ps[ja][q] += __shfl_xor(ps[ja][q], off, 64);
                pd[ja][q] += __shfl_xor(pd[ja][q], off, 64);
            }
    if (r == 0) {
        int Hh = F >> 6;
#pragma unroll
        for (int ja = 0; ja < 4; ++ja)
#pragma unroll
            for (int q = 0; q < 4; ++q) {
                int n = m0 + ja * 16 + g4 + q;
                if (n < Nn) {
                    a_s[(size_t)n * Hh + ft] = ps[ja][q];
                    a_d[(size_t)n * Hh + ft] = pd[ja][q];
                }
            }
    }
}

// ---------------- softmax + weighted aggregation (bucket CSR; round-8 proven) ----------------
template<int H>
__global__ void aggregate_kernel(const unsigned short* __restrict__ Hb,
                                 const float* __restrict__ a_s, const float* __restrict__ a_d,
                                 const int* __restrict__ cnt, const int* __restrict__ bucket,
                                 const int* __restrict__ ovd, const int* __restrict__ ovs,
                                 const int* __restrict__ n_over,
                                 const float* __restrict__ bias,
                                 unsigned short* __restrict__ out, int Nn)
{
    constexpr int F = H * 64;
    constexpr int VEC = F / 64;
    __shared__ uint2 s_pk[4][64][H];
    int w = threadIdx.x >> 6;
    int node = blockIdx.x * 4 + w;
    int lane = threadIdx.x & 63;
    if (node >= Nn) return;
    int deg = cnt[node];

    float adn[H];
#pragma unroll
    for (int h = 0; h < H; ++h) adn[h] = a_d[(size_t)node * H + h];

    if (deg <= 64) {
        // -------- fast path: whole neighborhood in lane registers --------
        bool act = lane < deg;
        int sn = act ? bucket[(size_t)node * 64 + lane] : 0;
        float v[H];
        if (H == 4) {
            const f32x4 av = *reinterpret_cast<const f32x4*>(a_s + (size_t)sn * 4);
#pragma unroll
            for (int h = 0; h < 4; ++h) {
                float t = av[h] + adn[h];
                t = (t > 0.f) ? t : NEG_SLOPE * t;
                v[h] = act ? t : -1e30f;
            }
        } else {
            float t = a_s[sn] + adn[0];
            t = (t > 0.f) ? t : NEG_SLOPE * t;
            v[0] = act ? t : -1e30f;
        }
        float m[H], e[H], s[H];
#pragma unroll
        for (int h = 0; h < H; ++h) {
            m[h] = v[h];
#pragma unroll
            for (int off = 32; off >= 1; off >>= 1)
                m[h] = fmaxf(m[h], __shfl_xor(m[h], off, 64));
        }
#pragma unroll
        for (int h = 0; h < H; ++h) {
            e[h] = act ? __expf(v[h] - m[h]) : 0.f;
            s[h] = e[h];
#pragma unroll
            for (int off = 32; off >= 1; off >>= 1)
                s[h] += __shfl_xor(s[h], off, 64);
        }

        // stage packed (src, exp) per head in LDS (own-wave slice; no barrier needed)
#pragma unroll
        for (int h = 0; h < H; ++h)
            s_pk[w][lane][h] = make_uint2((unsigned int)sn, __float_as_uint(e[h]));
        asm volatile("s_waitcnt lgkmcnt(0)" ::: "memory");

        if (H == 4) {
            // 8 edges / iter (2 batches of 4): 16 lanes per edge, 16 ch/lane
            int laneq = lane & 15, qtr = lane >> 4, hd = laneq >> 2;
            float2 acc2[8];
#pragma unroll
            for (int k = 0; k < 8; ++k) acc2[k] = make_float2(0.f, 0.f);
            int j = 0;
            for (; j + 8 <= deg; j += 8) {
                uint2 pkA = s_pk[w][j + qtr][hd];
                uint2 pkB = s_pk[w][j + 4 + qtr][hd];
                const uint4* hpA = reinterpret_cast<const uint4*>(Hb + (size_t)pkA.x * 256 + laneq * 16);
                const uint4* hpB = reinterpret_cast<const uint4*>(Hb + (size_t)pkB.x * 256 + laneq * 16);
                uint4 a0 = hpA[0];
                uint4 a1 = hpA[1];
                uint4 b0 = hpB[0];
                uint4 b1 = hpB[1];
                float exA = __uint_as_float(pkA.y);
                float exB = __uint_as_float(pkB.y);
                fma2(acc2[0], exA, a0.x); fma2(acc2[1], exA, a0.y);
                fma2(acc2[2], exA, a0.z); fma2(acc2[3], exA, a0.w);
                fma2(acc2[4], exA, a1.x); fma2(acc2[5], exA, a1.y);
                fma2(acc2[6], exA, a1.z); fma2(acc2[7], exA, a1.w);
                fma2(acc2[0], exB, b0.x); fma2(acc2[1], exB, b0.y);
                fma2(acc2[2], exB, b0.z); fma2(acc2[3], exB, b0.w);
                fma2(acc2[4], exB, b1.x); fma2(acc2[5], exB, b1.y);
                fma2(acc2[6], exB, b1.z); fma2(acc2[7], exB, b1.w);
            }
            for (; j < deg; j += 4) {
                uint2 pk = s_pk[w][j + qtr][hd];
                float ex = __uint_as_float(pk.y);
                const uint4* hp = reinterpret_cast<const uint4*>(Hb + (size_t)pk.x * 256 + laneq * 16);
                uint4 u0 = hp[0];
                uint4 u1 = hp[1];
                fma2(acc2[0], ex, u0.x); fma2(acc2[1], ex, u0.y);
                fma2(acc2[2], ex, u0.z); fma2(acc2[3], ex, u0.w);
                fma2(acc2[4], ex, u1.x); fma2(acc2[5], ex, u1.y);
                fma2(acc2[6], ex, u1.z); fma2(acc2[7], ex, u1.w);
            }
#pragma unroll
            for (int k = 0; k < 8; ++k) {
                acc2[k].x += __shfl_xor(acc2[k].x, 32, 64);
                acc2[k].y += __shfl_xor(acc2[k].y, 32, 64);
                acc2[k].x += __shfl_xor(acc2[k].x, 16, 64);
                acc2[k].y += __shfl_xor(acc2[k].y, 16, 64);
            }
            if (lane < 16) {
                int hd2 = lane >> 2;
                float sh = (hd2 == 0) ? s[0] : (hd2 == 1) ? s[1] : (hd2 == 2) ? s[2] : s[3];
                float inv = 1.f / (sh + 1e-16f);
                unsigned int pk8[8];
#pragma unroll
                for (int k = 0; k < 8; ++k) {
                    float t0 = acc2[k].x * inv + bias[lane * 16 + 2 * k];
                    float t1 = acc2[k].y * inv + bias[lane * 16 + 2 * k + 1];
                    unsigned int lo = f2bf(t0 > 0.f ? t0 : 0.f);
                    unsigned int hi = f2bf(t1 > 0.f ? t1 : 0.f);
                    pk8[k] = lo | (hi << 16);
                }
                uint4* op = reinterpret_cast<uint4*>(out + (size_t)node * 256 + lane * 16);
                op[0] = make_uint4(pk8[0], pk8[1], pk8[2], pk8[3]);
                op[1] = make_uint4(pk8[4], pk8[5], pk8[6], pk8[7]);
            }
        } else {
            // 16 edges / iter (2 batches of 8): 8 lanes per edge, 8 ch/lane
            int laneo = lane & 7, oct = lane >> 3;
            float2 acc2[4];
#pragma unroll
            for (int k = 0; k < 4; ++k) acc2[k] = make_float2(0.f, 0.f);
            int j = 0;
            for (; j + 16 <= deg; j += 16) {
                uint2 pkA = s_pk[w][j + oct][0];
                uint2 pkB = s_pk[w][j + 8 + oct][0];
                const uint4 a = *reinterpret_cast<const uint4*>(Hb + (size_t)pkA.x * 64 + laneo * 8);
                const uint4 b = *reinterpret_cast<const uint4*>(Hb + (size_t)pkB.x * 64 + laneo * 8);
                float exA = __uint_as_float(pkA.y);
                float exB = __uint_as_float(pkB.y);
                fma2(acc2[0], exA, a.x); fma2(acc2[1], exA, a.y);
                fma2(acc2[2], exA, a.z); fma2(acc2[3], exA, a.w);
                fma2(acc2[0], exB, b.x); fma2(acc2[1], exB, b.y);
                fma2(acc2[2], exB, b.z); fma2(acc2[3], exB, b.w);
            }
            for (; j < deg; j += 8) {
                uint2 pk = s_pk[w][j + oct][0];
                float ex = __uint_as_float(pk.y);
                const uint4 u = *reinterpret_cast<const uint4*>(Hb + (size_t)pk.x * 64 + laneo * 8);
                fma2(acc2[0], ex, u.x); fma2(acc2[1], ex, u.y);
                fma2(acc2[2], ex, u.z); fma2(acc2[3], ex, u.w);
            }
#pragma unroll
            for (int k = 0; k < 4; ++k) {
                acc2[k].x += __shfl_xor(acc2[k].x, 32, 64);
                acc2[k].y += __shfl_xor(acc2[k].y, 32, 64);
                acc2[k].x += __shfl_xor(acc2[k].x, 16, 64);
                acc2[k].y += __shfl_xor(acc2[k].y, 16, 64);
                acc2[k].x += __shfl_xor(acc2[k].x, 8, 64);
                acc2[k].y += __shfl_xor(acc2[k].y, 8, 64);
            }
            if (lane < 8) {
                float inv = 1.f / (s[0] + 1e-16f);
                unsigned int pk4[4];
#pragma unroll
                for (int k = 0; k < 4; ++k) {
                    float t0 = acc2[k].x * inv + bias[lane * 8 + 2 * k];
                    float t1 = acc2[k].y * inv + bias[lane * 8 + 2 * k + 1];
                    unsigned int lo = f2bf(t0 > 0.f ? t0 : 0.f);
                    unsigned int hi = f2bf(t1 > 0.f ? t1 : 0.f);
                    pk4[k] = lo | (hi << 16);
                }
                *reinterpret_cast<uint4*>(out + (size_t)node * 64 + lane * 8) =
                    make_uint4(pk4[0], pk4[1], pk4[2], pk4[3]);
            }
        }
        return;
    }

    // -------- slow path (deg > 64): bucket (64 entries) + overflow list; exact --------
    int nov = *n_over;
    int head = (H == 1) ? 0 : (lane >> 4);
    float m[H], s[H];
#pragma unroll
    for (int h = 0; h < H; ++h) { m[h] = -1e30f; s[h] = 0.f; }
    {
        int sn = bucket[(size_t)node * 64 + lane];
#pragma unroll
        for (int h = 0; h < H; ++h) {
            float t = a_s[(size_t)sn * H + h] + adn[h];
            t = (t > 0.f) ? t : NEG_SLOPE * t;
            m[h] = fmaxf(m[h], t);
        }
    }
    for (int i = lane; i < nov; i += 64) {
        if (ovd[i] != node) continue;
        int sn = ovs[i];
#pragma unroll
        for (int h = 0; h < H; ++h) {
            float t = a_s[(size_t)sn * H + h] + adn[h];
            t = (t > 0.f) ? t : NEG_SLOPE * t;
            m[h] = fmaxf(m[h], t);
        }
    }
#pragma unroll
    for (int off = 32; off >= 1; off >>= 1)
#pragma unroll
        for (int h = 0; h < H; ++h) m[h] = fmaxf(m[h], __shfl_xor(m[h], off, 64));
    {
        int sn = bucket[(size_t)node * 64 + lane];
#pragma unroll
        for (int h = 0; h < H; ++h) {
            float t = a_s[(size_t)sn * H + h] + adn[h];
            t = (t > 0.f) ? t : NEG_SLOPE * t;
            s[h] += __expf(t - m[h]);
        }
    }
    for (int i = lane; i < nov; i += 64) {
        if (ovd[i] != node) continue;
        int sn = ovs[i];
#pragma unroll
        for (int h = 0; h < H; ++h) {
            float t = a_s[(size_t)sn * H + h] + adn[h];
            t = (t > 0.f) ? t : NEG_SLOPE * t;
            s[h] += __expf(t - m[h]);
        }
    }
#pragma unroll
    for (int off = 32; off >= 1; off >>= 1)
#pragma unroll
        for (int h = 0; h < H; ++h) s[h] += __shfl_xor(s[h], off, 64);

    float mh, sh, adh;
    if (H == 1) { mh = m[0]; sh = s[0]; adh = adn[0]; }
    else {
        mh  = (head == 0) ? m[0]   : (head == 1) ? m[1]   : (head == 2) ? m[2]   : m[3];
        sh  = (head == 0) ? s[0]   : (head == 1) ? s[1]   : (head == 2) ? s[2]   : s[3];
        adh = (head == 0) ? adn[0] : (head == 1) ? adn[1] : (head == 2) ? adn[2] : adn[3];
    }
    float inv = 1.f / (sh + 1e-16f);
    float acc[VEC];
#pragma unroll
    for (int k = 0; k < VEC; ++k) acc[k] = 0.f;
    for (int j = 0; j < 64; ++j) {
        int sn = bucket[(size_t)node * 64 + j];
        float t = a_s[(size_t)sn * H + head] + adh;
        t = (t > 0.f) ? t : NEG_SLOPE * t;
        float ex = __expf(t - mh);
        const unsigned short* hp = Hb + (size_t)sn * F + lane * VEC;
#pragma unroll
        for (int k = 0; k < VEC; ++k) acc[k] += ex * bf2f(hp[k]);
    }
    for (int i = 0; i < nov; ++i) {
        if (ovd[i] != node) continue;
        int sn = ovs[i];
        float t = a_s[(size_t)sn * H + head] + adh;
        t = (t > 0.f) ? t : NEG_SLOPE * t;
        float ex = __expf(t - mh);
        const unsigned short* hp = Hb + (size_t)sn * F + lane * VEC;
#pragma unroll
        for (int k = 0; k < VEC; ++k) acc[k] += ex * bf2f(hp[k]);
    }
#pragma unroll
    for (int k = 0; k < VEC; ++k) {
        int f = lane * VEC + k;
        float t = acc[k] * inv + bias[f];
        out[(size_t)node * F + f] = f2bf(t > 0.f ? t : 0.f);
    }
}

// ---------------- global mean pool (sums, bf16 input) ----------------
__global__ void pool_kernel(const unsigned short* __restrict__ x, const int* __restrict__ batch,
                            float* __restrict__ gsums, int Nn)
{
    int lane = threadIdx.x;        // blockDim = 64
    int n0 = blockIdx.x * 64;
    if (n0 >= Nn) return;
    int nend = min(n0 + 64, Nn);
    float acc = 0.f;
    int gcur = batch[n0];
    for (int n = n0; n < nend; ++n) {
        int g = batch[n];
        if (g != gcur) {
            atomicAdd(&gsums[gcur * 64 + lane], acc);
            acc = 0.f;
            gcur = g;
        }
        acc += bf2f(x[(size_t)n * 64 + lane]);
    }
    atomicAdd(&gsums[gcur * 64 + lane], acc);
}

// ---------------- final linear ----------------
__global__ void final_kernel(const float* __restrict__ gsums, const int* __restrict__ gcnt,
                             const float* __restrict__ linW, const float* __restrict__ linb,
                             float* __restrict__ out, int G)
{
    int t = threadIdx.x;
    if (t >= G * 10) return;
    int g = t / 10, j = t % 10;
    float cnt = (float)max(gcnt[g], 1);
    float acc = 0.f;
#pragma unroll
    for (int c = 0; c < 64; ++c) acc += gsums[g * 64 + c] * linW[j * 64 + c];
    out[g * 10 + j] = acc / cnt + linb[j];
}

extern "C" void kernel_launch(void* const* d_in, const int* in_sizes, int n_in,
                              void* d_out, int out_size, void* d_ws, size_t ws_size,
                              hipStream_t stream)
{
    const int*   x_ids    = (const int*)d_in[0];
    const float* degrees  = (const float*)d_in[1];
    const int*   edge_src = (const int*)d_in[2];
    const int*   edge_dst = (const int*)d_in[3];
    const int*   batch    = (const int*)d_in[4];
    const float* emb      = (const float*)d_in[5];
    const float* W1  = (const float*)d_in[6];
    const float* as1 = (const float*)d_in[7];
    const float* ad1 = (const float*)d_in[8];
    const float* b1  = (const float*)d_in[9];
    const float* W2  = (const float*)d_in[10];
    const float* as2 = (const float*)d_in[11];
    const float* ad2 = (const float*)d_in[12];
    const float* b2  = (const float*)d_in[13];
    const float* W3  = (const float*)d_in[14];
    const float* as3 = (const float*)d_in[15];
    const float* ad3 = (const float*)d_in[16];
    const float* b3  = (const float*)d_in[17];
    const float* linW = (const float*)d_in[18];
    const float* linb = (const float*)d_in[19];

    const int N  = in_sizes[0];
    const int E0 = in_sizes[2];
    const int E2 = E0 + N;
    const int G  = out_size / 10;
    const int nW1 = in_sizes[6], nW2 = in_sizes[10], nW3 = in_sizes[14];

    char* p = (char*)d_ws;
    size_t off = 0;
    auto take = [&](size_t bytes) {
        void* q = p + off;
        off = (off + bytes + 255) & ~(size_t)255;
        return q;
    };
    unsigned short* xA  = (unsigned short*)take((size_t)N * 256 * 2);
    unsigned short* xB  = (unsigned short*)take((size_t)N * 256 * 2);
    float* a_s     = (float*)take((size_t)N * 4 * 4);
    float* a_d     = (float*)take((size_t)N * 4 * 4);
    int*   cnt     = (int*)take((size_t)(N + 64) * 4);   // cnt[N] followed by n_over
    int*   n_over  = cnt + N;
    int*   bucket  = (int*)take((size_t)N * 64 * 4);
    int*   ovd     = (int*)take((size_t)E2 * 4);
    int*   ovs     = (int*)take((size_t)E2 * 4);
    float* gsums   = (float*)take((size_t)G * 64 * 4);
    int*   gcnt    = (int*)take((size_t)G * 4);
    unsigned short* w1b = (unsigned short*)take((size_t)nW1 * 2);
    unsigned short* w2b = (unsigned short*)take((size_t)nW2 * 2);
    unsigned short* w3b = (unsigned short*)take((size_t)nW3 * 2);

    hipMemsetAsync(gsums, 0, (size_t)G * 64 * 4, stream);

    const int nodeBlocks4 = (N + 3) / 4;

    // prep block partition
    const int nWtot = nW1 + nW2 + nW3;
    const int bW = (nWtot + 255) / 256;
    const int bX = bW + nodeBlocks4;
    prep_kernel<<<bX + 1, 256, 0, stream>>>(W1, nW1, W2, nW2, W3, nW3, w1b, w2b, w3b,
                                            x_ids, degrees, emb, xA,
                                            cnt, bucket, n_over, batch, gcnt,
                                            N, G, bW, bX);

    const int mtiles = (N + 63) / 64;
    auto gemmBlocks = [&](int ftiles) { return (mtiles * ftiles + 3) / 4; };

    // ---- layer 1 (fused with edge scatter): 64 -> 4x64 concat ----
    const int gemmB1   = gemmBlocks(4);
    const int scatterB = (E0 + 2047) / 2048;
    gemm_scatter<<<gemmB1 + scatterB, 256, 0, stream>>>(xA, w1b, xB, as1, ad1, a_s, a_d,
                                                        N, 64, 256, gemmB1,
                                                        edge_src, edge_dst, cnt, bucket,
                                                        ovd, ovs, n_over, E0);
    aggregate_kernel<4><<<nodeBlocks4, 256, 0, stream>>>(xB, a_s, a_d, cnt, bucket, ovd, ovs, n_over, b1, xA, N);
    // ---- layer 2: 256 -> 4x64 concat ----
    gemm_mfma<<<gemmBlocks(4), 256, 0, stream>>>(xA, w2b, xB, as2, ad2, a_s, a_d, N, 256, 256);
    aggregate_kernel<4><<<nodeBlocks4, 256, 0, stream>>>(xB, a_s, a_d, cnt, bucket, ovd, ovs, n_over, b2, xA, N);
    // ---- layer 3: 256 -> 1x64 (mean == identity) ----
    gemm_mfma<<<gemmBlocks(1), 256, 0, stream>>>(xA, w3b, xB, as3, ad3, a_s, a_d, N, 256, 64);
    aggregate_kernel<1><<<nodeBlocks4, 256, 0, stream>>>(xB, a_s, a_d, cnt, bucket, ovd, ovs, n_over, b3, xA, N);

    pool_kernel<<<(N + 63) / 64, 64, 0, stream>>>(xA, batch, gsums, N);
    final_kernel<<<1, ((G * 10 + 63) / 64) * 64, 0, stream>>>(gsums, gcnt, linW, linb, (float*)d_out, G);
}